// Round 15
// baseline (316.182 us; speedup 1.0000x reference)
//
#include <hip/hip_runtime.h>

#define N_NODES 100000
#define E_EDGES 1600000
#define F_IN    128
#define H_DIM   64
#define C_OUT   16
#define L_LAYERS 3
#define NTOT    (E_EDGES + N_NODES)
#define MAXD    64    // LDS-staged degree cap in agg; fallback recomputes

#define BKN2    512
#define NB2     ((N_NODES + BKN2 - 1) / BKN2)         // 196
#define BCAP    9216
#define CH      8192
#define PB      ((E_EDGES + CH - 1) / CH)             // 196

typedef __attribute__((ext_vector_type(8))) short short8;
typedef __attribute__((ext_vector_type(4))) float f32x4;

// bf16 helpers
__device__ inline unsigned short f2bf(float f) {
    unsigned u = __float_as_uint(f);
    return (unsigned short)((u + 0x7FFFu + ((u >> 16) & 1u)) >> 16);
}
__device__ inline float bf_lo(unsigned p) { return __uint_as_float(p << 16); }
__device__ inline float bf_hi(unsigned p) { return __uint_as_float(p & 0xFFFF0000u); }
__device__ inline unsigned cvt_pk_bf16(float lo, float hi) {
    unsigned r;
    asm("v_cvt_pk_bf16_f32 %0, %1, %2" : "=v"(r) : "v"(lo), "v"(hi));
    return r;
}

// ---------------- pass B: block-local bucket sort + dense scatter ----------------
__global__ __launch_bounds__(256) void bucket_scatter2(
        const void* __restrict__ eidx,
        int* __restrict__ bcur, unsigned int* __restrict__ packed) {
    __shared__ int cnt[NB2], basel[NB2], curl[NB2], gbase[NB2];
    __shared__ int sd[256];
    __shared__ int sflag;
    __shared__ unsigned int stage[CH];
    __shared__ unsigned char bkt[CH];
    int t = threadIdx.x;
    int b0 = blockIdx.x * CH;
    int ne = min(CH, E_EDGES - b0);
    if (t == 0) sflag = 0;
    for (int i = t; i < NB2; i += 256) cnt[i] = 0;
    __syncthreads();
    {
        int nsamp = min(ne, 1024);
        int any = 0;
        for (int j = t; j < nsamp; j += 256)
            if (((const unsigned*)eidx)[2 * (size_t)(b0 + j) + 1] != 0u) any = 1;
        if (any) atomicOr(&sflag, 1);
    }
    __syncthreads();
    int f64 = sflag ? 0 : 1;

    int es[CH / 256], ed[CH / 256];
    #pragma unroll
    for (int j = 0; j < CH / 256; ++j) {
        int idx = b0 + j * 256 + t;
        if (idx < E_EDGES) {
            if (f64) {
                es[j] = (int)((const long long*)eidx)[idx];
                ed[j] = (int)((const long long*)eidx)[E_EDGES + idx];
            } else {
                es[j] = ((const int*)eidx)[idx];
                ed[j] = ((const int*)eidx)[E_EDGES + idx];
            }
            atomicAdd(&cnt[ed[j] >> 9], 1);
        } else { es[j] = -1; }
    }
    __syncthreads();
    int v = (t < NB2) ? cnt[t] : 0;
    sd[t] = v;
    __syncthreads();
    for (int off = 1; off < 256; off <<= 1) {
        int u = (t >= off) ? sd[t - off] : 0;
        __syncthreads();
        sd[t] += u;
        __syncthreads();
    }
    if (t < NB2) {
        basel[t] = sd[t] - v;
        curl[t] = 0;
        gbase[t] = atomicAdd(&bcur[t], v);
    }
    __syncthreads();
    #pragma unroll
    for (int j = 0; j < CH / 256; ++j) {
        if (es[j] >= 0) {
            int b = ed[j] >> 9;
            int r = atomicAdd(&curl[b], 1);
            int pos = basel[b] + r;
            stage[pos] = ((unsigned)(ed[j] & (BKN2 - 1)) << 17) | (unsigned)es[j];
            bkt[pos] = (unsigned char)b;
        }
    }
    __syncthreads();
    for (int i = t; i < ne; i += 256) {
        int b = bkt[i];
        packed[(size_t)b * BCAP + gbase[b] + (i - basel[b])] = stage[i];
    }
}

// ---------------- pass C: per-bucket CSR finalize (inline bucket prefix) ------
__global__ __launch_bounds__(256) void csr_build2(
        const unsigned int* __restrict__ packed, const int* __restrict__ bcur,
        int* __restrict__ row_ptr, int* __restrict__ csr_src) {
    __shared__ int cnt[BKN2], scn[BKN2], cur[BKN2];
    int b = blockIdx.x, t = threadIdx.x;
    scn[t] = (t < b) ? bcur[t] : 0;
    __syncthreads();
    for (int off = 128; off >= 1; off >>= 1) {
        if (t < off) scn[t] += scn[t + off];
        __syncthreads();
    }
    int ebase_b = scn[0];
    __syncthreads();

    int nbase = b * BKN2;
    int nn = min(BKN2, N_NODES - nbase);
    int ec = bcur[b];
    size_t pbase = (size_t)b * BCAP;
    int cbase = ebase_b + nbase;
    cnt[t] = (t < nn) ? 1 : 0;
    cnt[t + 256] = (t + 256 < nn) ? 1 : 0;
    __syncthreads();
    for (int i = t; i < ec; i += 256)
        atomicAdd(&cnt[packed[pbase + i] >> 17], 1);
    __syncthreads();
    scn[t] = cnt[t];
    scn[t + 256] = cnt[t + 256];
    __syncthreads();
    for (int off = 1; off < BKN2; off <<= 1) {
        int u0 = (t >= off) ? scn[t - off] : 0;
        int u1 = (t + 256 >= off) ? scn[t + 256 - off] : 0;
        __syncthreads();
        scn[t] += u0;
        scn[t + 256] += u1;
        __syncthreads();
    }
    #pragma unroll
    for (int q = 0; q < 2; ++q) {
        int idx = t + q * 256;
        if (idx < nn) {
            int offi = scn[idx] - cnt[idx];
            row_ptr[nbase + idx] = cbase + offi;
            csr_src[cbase + offi] = nbase + idx;   // self-loop first
            cur[idx] = offi + 1;
        }
    }
    if (b == NB2 - 1 && t == 0) row_ptr[N_NODES] = cbase + ec + nn;
    __syncthreads();
    for (int i = t; i < ec; i += 256) {
        unsigned p = packed[pbase + i];
        int dl = p >> 17, s = (int)(p & 0x1FFFFu);
        int pos = atomicAdd(&cur[dl], 1);
        csr_src[cbase + pos] = s;
    }
}

// ---------------- MFMA input GEMM (R13 exact) ----------------
#define SAW 136   // bf16 row stride for sA/sWT (pad 8)

__global__ __launch_bounds__(256) void gemm_in_mfma(
        const float* __restrict__ X, const float* __restrict__ W,
        const float* __restrict__ bias, unsigned* __restrict__ C) {
    __shared__ __align__(16) unsigned short sA[64][SAW];
    __shared__ __align__(16) unsigned short sWT[64][SAW];
    __shared__ float sB[64];
    int t = threadIdx.x;
    int r0 = blockIdx.x * 64;
    #pragma unroll
    for (int it = 0; it < 8; ++it) {
        int idx = it * 256 + t;
        int r = idx >> 5, c4 = (idx & 31) * 4;
        int gr = r0 + r;
        float4 v = make_float4(0.f, 0.f, 0.f, 0.f);
        if (gr < N_NODES) v = *(const float4*)&X[(size_t)gr * F_IN + c4];
        unsigned* dst = (unsigned*)&sA[r][c4];
        dst[0] = cvt_pk_bf16(v.x, v.y);
        dst[1] = cvt_pk_bf16(v.z, v.w);
    }
    #pragma unroll
    for (int it = 0; it < 8; ++it) {
        int idx = it * 256 + t;
        int k = idx >> 4, j4 = (idx & 15) * 4;
        float4 v = *(const float4*)&W[k * 64 + j4];
        sWT[j4 + 0][k] = f2bf(v.x);
        sWT[j4 + 1][k] = f2bf(v.y);
        sWT[j4 + 2][k] = f2bf(v.z);
        sWT[j4 + 3][k] = f2bf(v.w);
    }
    if (t < 64) sB[t] = bias[t];
    __syncthreads();

    int wave = t >> 6, lane = t & 63;
    int cj = lane & 15, kq = lane >> 4;
    int lrow = wave * 16 + cj;
    f32x4 zero = {0.f, 0.f, 0.f, 0.f};
    f32x4 acc[4] = {zero, zero, zero, zero};
    #pragma unroll
    for (int q = 0; q < 4; ++q) {
        short8 a = *(const short8*)&sA[lrow][q * 32 + kq * 8];
        #pragma unroll
        for (int ct = 0; ct < 4; ++ct) {
            short8 bfr = *(const short8*)&sWT[ct * 16 + cj][q * 32 + kq * 8];
            acc[ct] = __builtin_amdgcn_mfma_f32_16x16x32_bf16(a, bfr, acc[ct], 0, 0, 0);
        }
    }
    __syncthreads();
    float* tl = (float*)&sA[0][0] + wave * (16 * 65);
    #pragma unroll
    for (int ct = 0; ct < 4; ++ct) {
        float bsv = sB[ct * 16 + cj];
        #pragma unroll
        for (int r = 0; r < 4; ++r) {
            float v = acc[ct][r] + bsv;
            v = v > 0.f ? v : 0.01f * v;
            tl[(kq * 4 + r) * 65 + ct * 16 + cj] = v;
        }
    }
    unsigned ur[8];
    int trow = lane >> 2, tcb = lane & 3;
    #pragma unroll
    for (int i = 0; i < 8; ++i) {
        float2 fp = *(const float2*)&tl[trow * 65 + tcb * 16 + i * 2];
        ur[i] = cvt_pk_bf16(fp.x, fp.y);
    }
    int grow = r0 + wave * 16 + trow;
    if (grow < N_NODES) {
        uint4* dst = (uint4*)&C[(size_t)grow * 32 + tcb * 8];
        dst[0] = make_uint4(ur[0], ur[1], ur[2], ur[3]);
        dst[1] = make_uint4(ur[4], ur[5], ur[6], ur[7]);
    }
}

// ---------------- MFMA layer GEMM (R13 exact) ----------------
__global__ __launch_bounds__(256) void gemm_mfma_kernel(
        const unsigned* __restrict__ A32, const float* __restrict__ W,
        const float* __restrict__ asrc, const float* __restrict__ adst,
        unsigned* __restrict__ C, float* __restrict__ as_, float* __restrict__ ad_) {
    __shared__ __align__(16) unsigned short sWT[64][72];
    __shared__ float sAv[64], sDv[64];
    __shared__ __align__(16) float sTile[4][16 * 65];
    int t = threadIdx.x;
    for (int i = t; i < 64 * 64; i += 256) {
        int k = i >> 6, j = i & 63;
        sWT[j][k] = f2bf(W[i]);
    }
    if (t < 64) { sAv[t] = asrc[t]; sDv[t] = adst[t]; }
    __syncthreads();

    int wave = t >> 6, lane = t & 63;
    int r0 = blockIdx.x * 64 + wave * 16;
    int cj = lane & 15, kq = lane >> 4;

    int ra = r0 + cj;
    if (ra >= N_NODES) ra = N_NODES - 1;
    const short8* arow = (const short8*)&A32[(size_t)ra * 32];
    short8 a0 = arow[kq];
    short8 a1 = arow[4 + kq];

    f32x4 zero = {0.f, 0.f, 0.f, 0.f};
    f32x4 acc[4] = {zero, zero, zero, zero};
    #pragma unroll
    for (int ct = 0; ct < 4; ++ct) {
        short8 b0 = *(const short8*)&sWT[16 * ct + cj][kq * 8];
        short8 b1 = *(const short8*)&sWT[16 * ct + cj][32 + kq * 8];
        acc[ct] = __builtin_amdgcn_mfma_f32_16x16x32_bf16(a0, b0, acc[ct], 0, 0, 0);
        acc[ct] = __builtin_amdgcn_mfma_f32_16x16x32_bf16(a1, b1, acc[ct], 0, 0, 0);
    }

    float av[4], dv[4];
    #pragma unroll
    for (int ct = 0; ct < 4; ++ct) { av[ct] = sAv[ct * 16 + cj]; dv[ct] = sDv[ct * 16 + cj]; }
    #pragma unroll
    for (int r = 0; r < 4; ++r) {
        float ds = acc[0][r] * av[0] + acc[1][r] * av[1] + acc[2][r] * av[2] + acc[3][r] * av[3];
        float dd = acc[0][r] * dv[0] + acc[1][r] * dv[1] + acc[2][r] * dv[2] + acc[3][r] * dv[3];
        #pragma unroll
        for (int off = 1; off < 16; off <<= 1) {
            ds += __shfl_xor(ds, off);
            dd += __shfl_xor(dd, off);
        }
        int grow = r0 + kq * 4 + r;
        if (cj == 0 && grow < N_NODES) { as_[grow] = ds; ad_[grow] = dd; }
    }

    float* tl = sTile[wave];
    #pragma unroll
    for (int ct = 0; ct < 4; ++ct)
        #pragma unroll
        for (int r = 0; r < 4; ++r)
            tl[(kq * 4 + r) * 65 + ct * 16 + cj] = acc[ct][r];
    unsigned ur[8];
    int trow = lane >> 2, tcb = lane & 3;
    #pragma unroll
    for (int i = 0; i < 8; ++i) {
        float2 fp = *(const float2*)&tl[trow * 65 + tcb * 16 + i * 2];
        ur[i] = cvt_pk_bf16(fp.x, fp.y);
    }
    int grow = r0 + trow;
    if (grow < N_NODES) {
        uint4* dst = (uint4*)&C[(size_t)grow * 32 + tcb * 8];
        dst[0] = make_uint4(ur[0], ur[1], ur[2], ur[3]);
        dst[1] = make_uint4(ur[4], ur[5], ur[6], ur[7]);
    }
}

// ---------------- aggregation (R13 exact: 16-lane groups, 2-deep unroll) ----
__global__ __launch_bounds__(256) void agg_kernel(
        const int* __restrict__ row_ptr, const int* __restrict__ csr_src,
        const float* __restrict__ as_, const float* __restrict__ ad_,
        const unsigned* __restrict__ hw32, const float* __restrict__ bc,
        unsigned* __restrict__ hout32) {
    __shared__ float exbuf[4][MAXD];
    __shared__ int   sbuf[4][MAXD];
    int wave = threadIdx.x >> 6, lane = threadIdx.x & 63;
    int node = blockIdx.x * 4 + wave;
    if (node >= N_NODES) return;
    int rs = row_ptr[node], re = row_ptr[node + 1];
    int deg = re - rs;
    float aD = ad_[node];
    float psum = 0.f;
    for (int i = lane; i < deg; i += 64) {
        int s = csr_src[rs + i];
        float v = as_[s] + aD;
        v = v > 0.f ? v : 0.2f * v;
        float p = __expf(v);
        if (deg <= MAXD) { exbuf[wave][i] = p; sbuf[wave][i] = s; }
        psum += p;
    }
    #pragma unroll
    for (int off = 32; off >= 1; off >>= 1) psum += __shfl_xor(psum, off);
    float inv = 1.f / (psum + 1e-16f);

    int g = lane >> 4, fl16 = lane & 15;
    float a0 = 0.f, a1 = 0.f, a2 = 0.f, a3 = 0.f;
    if (deg <= MAXD) {
        int i = g;
        for (; i + 4 < deg; i += 8) {
            float w0 = exbuf[wave][i], w1 = exbuf[wave][i + 4];
            int s0 = sbuf[wave][i], s1 = sbuf[wave][i + 4];
            uint2 p0 = *(const uint2*)&hw32[((unsigned)s0 << 5) | (fl16 * 2)];
            uint2 p1 = *(const uint2*)&hw32[((unsigned)s1 << 5) | (fl16 * 2)];
            a0 += w0 * bf_lo(p0.x) + w1 * bf_lo(p1.x);
            a1 += w0 * bf_hi(p0.x) + w1 * bf_hi(p1.x);
            a2 += w0 * bf_lo(p0.y) + w1 * bf_lo(p1.y);
            a3 += w0 * bf_hi(p0.y) + w1 * bf_hi(p1.y);
        }
        for (; i < deg; i += 4) {
            float w = exbuf[wave][i];
            int s = sbuf[wave][i];
            uint2 p = *(const uint2*)&hw32[((unsigned)s << 5) | (fl16 * 2)];
            a0 += w * bf_lo(p.x);
            a1 += w * bf_hi(p.x);
            a2 += w * bf_lo(p.y);
            a3 += w * bf_hi(p.y);
        }
    } else {
        for (int i = g; i < deg; i += 4) {
            int s = csr_src[rs + i];
            float v = as_[s] + aD;
            v = v > 0.f ? v : 0.2f * v;
            float w = __expf(v);
            uint2 p = *(const uint2*)&hw32[((unsigned)s << 5) | (fl16 * 2)];
            a0 += w * bf_lo(p.x);
            a1 += w * bf_hi(p.x);
            a2 += w * bf_lo(p.y);
            a3 += w * bf_hi(p.y);
        }
    }
    a0 += __shfl_xor(a0, 16); a0 += __shfl_xor(a0, 32);
    a1 += __shfl_xor(a1, 16); a1 += __shfl_xor(a1, 32);
    a2 += __shfl_xor(a2, 16); a2 += __shfl_xor(a2, 32);
    a3 += __shfl_xor(a3, 16); a3 += __shfl_xor(a3, 32);
    if (g == 0) {
        float4 bv = *(const float4*)&bc[fl16 * 4];
        float v0 = a0 * inv + bv.x; v0 = v0 > 0.f ? v0 : 0.01f * v0;
        float v1 = a1 * inv + bv.y; v1 = v1 > 0.f ? v1 : 0.01f * v1;
        float v2 = a2 * inv + bv.z; v2 = v2 > 0.f ? v2 : 0.01f * v2;
        float v3 = a3 * inv + bv.w; v3 = v3 > 0.f ? v3 : 0.01f * v3;
        *(uint2*)&hout32[((unsigned)node << 5) | (fl16 * 2)] =
            make_uint2(cvt_pk_bf16(v0, v1), cvt_pk_bf16(v2, v3));
    }
}

// ---------------- layer-3 aggregation + output GEMM + log_softmax -----------
// Identical agg body; epilogue keeps h row in wave-local LDS (fp32) and lanes
// 0-15 compute the 16 logits + width-16 softmax. Separate kernel (no template
// sharing with agg_kernel -> codegen isolation, rule #19).
__global__ __launch_bounds__(256) void agg_out_kernel(
        const int* __restrict__ row_ptr, const int* __restrict__ csr_src,
        const float* __restrict__ as_, const float* __restrict__ ad_,
        const unsigned* __restrict__ hw32, const float* __restrict__ bc,
        const float* __restrict__ Wo, const float* __restrict__ bo,
        float* __restrict__ out) {
    __shared__ float exbuf[4][MAXD];
    __shared__ int   sbuf[4][MAXD];
    __shared__ float sh[4][64];
    __shared__ float sWo[64 * 16];
    __shared__ float sbo[16];
    int t = threadIdx.x;
    for (int i = t; i < 64 * 16; i += 256) sWo[i] = Wo[i];
    if (t < 16) sbo[t] = bo[t];
    __syncthreads();

    int wave = t >> 6, lane = t & 63;
    int node = blockIdx.x * 4 + wave;
    if (node >= N_NODES) return;
    int rs = row_ptr[node], re = row_ptr[node + 1];
    int deg = re - rs;
    float aD = ad_[node];
    float psum = 0.f;
    for (int i = lane; i < deg; i += 64) {
        int s = csr_src[rs + i];
        float v = as_[s] + aD;
        v = v > 0.f ? v : 0.2f * v;
        float p = __expf(v);
        if (deg <= MAXD) { exbuf[wave][i] = p; sbuf[wave][i] = s; }
        psum += p;
    }
    #pragma unroll
    for (int off = 32; off >= 1; off >>= 1) psum += __shfl_xor(psum, off);
    float inv = 1.f / (psum + 1e-16f);

    int g = lane >> 4, fl16 = lane & 15;
    float a0 = 0.f, a1 = 0.f, a2 = 0.f, a3 = 0.f;
    if (deg <= MAXD) {
        int i = g;
        for (; i + 4 < deg; i += 8) {
            float w0 = exbuf[wave][i], w1 = exbuf[wave][i + 4];
            int s0 = sbuf[wave][i], s1 = sbuf[wave][i + 4];
            uint2 p0 = *(const uint2*)&hw32[((unsigned)s0 << 5) | (fl16 * 2)];
            uint2 p1 = *(const uint2*)&hw32[((unsigned)s1 << 5) | (fl16 * 2)];
            a0 += w0 * bf_lo(p0.x) + w1 * bf_lo(p1.x);
            a1 += w0 * bf_hi(p0.x) + w1 * bf_hi(p1.x);
            a2 += w0 * bf_lo(p0.y) + w1 * bf_lo(p1.y);
            a3 += w0 * bf_hi(p0.y) + w1 * bf_hi(p1.y);
        }
        for (; i < deg; i += 4) {
            float w = exbuf[wave][i];
            int s = sbuf[wave][i];
            uint2 p = *(const uint2*)&hw32[((unsigned)s << 5) | (fl16 * 2)];
            a0 += w * bf_lo(p.x);
            a1 += w * bf_hi(p.x);
            a2 += w * bf_lo(p.y);
            a3 += w * bf_hi(p.y);
        }
    } else {
        for (int i = g; i < deg; i += 4) {
            int s = csr_src[rs + i];
            float v = as_[s] + aD;
            v = v > 0.f ? v : 0.2f * v;
            float w = __expf(v);
            uint2 p = *(const uint2*)&hw32[((unsigned)s << 5) | (fl16 * 2)];
            a0 += w * bf_lo(p.x);
            a1 += w * bf_hi(p.x);
            a2 += w * bf_lo(p.y);
            a3 += w * bf_hi(p.y);
        }
    }
    a0 += __shfl_xor(a0, 16); a0 += __shfl_xor(a0, 32);
    a1 += __shfl_xor(a1, 16); a1 += __shfl_xor(a1, 32);
    a2 += __shfl_xor(a2, 16); a2 += __shfl_xor(a2, 32);
    a3 += __shfl_xor(a3, 16); a3 += __shfl_xor(a3, 32);
    if (g == 0) {
        float4 bv = *(const float4*)&bc[fl16 * 4];
        float v0 = a0 * inv + bv.x; v0 = v0 > 0.f ? v0 : 0.01f * v0;
        float v1 = a1 * inv + bv.y; v1 = v1 > 0.f ? v1 : 0.01f * v1;
        float v2 = a2 * inv + bv.z; v2 = v2 > 0.f ? v2 : 0.01f * v2;
        float v3 = a3 * inv + bv.w; v3 = v3 > 0.f ? v3 : 0.01f * v3;
        sh[wave][fl16 * 4 + 0] = v0;
        sh[wave][fl16 * 4 + 1] = v1;
        sh[wave][fl16 * 4 + 2] = v2;
        sh[wave][fl16 * 4 + 3] = v3;
        // wave-local LDS RAW (same 16 lanes write + read): lgkmcnt ordering
        float acc = sbo[fl16];
        #pragma unroll 8
        for (int k = 0; k < 64; ++k) acc += sh[wave][k] * sWo[k * 16 + fl16];
        float m = acc;
        #pragma unroll
        for (int off = 8; off >= 1; off >>= 1) m = fmaxf(m, __shfl_xor(m, off, 16));
        float e = __expf(acc - m);
        float ssum = e;
        #pragma unroll
        for (int off = 8; off >= 1; off >>= 1) ssum += __shfl_xor(ssum, off, 16);
        out[(size_t)node * C_OUT + fl16] = acc - m - __logf(ssum);
    }
}

extern "C" void kernel_launch(void* const* d_in, const int* in_sizes, int n_in,
                              void* d_out, int out_size, void* d_ws, size_t ws_size,
                              hipStream_t stream) {
    const float* x     = (const float*)d_in[0];
    const void*  eidx  = d_in[1];
    const float* W_in  = (const float*)d_in[3];
    const float* b_in  = (const float*)d_in[4];
    const float* Wc    = (const float*)d_in[5];
    const float* a_src = (const float*)d_in[6];
    const float* a_dst = (const float*)d_in[7];
    const float* bc    = (const float*)d_in[8];
    const float* W_out = (const float*)d_in[9];
    const float* b_out = (const float*)d_in[10];
    float* out = (float*)d_out;

    // workspace: h, hw packed-bf16 node tables (N x 32 uints)
    unsigned* h     = (unsigned*)d_ws;                     // N*32 uints
    unsigned* hw    = h + (size_t)N_NODES * 32;            // N*32 uints
    float* as_      = (float*)(hw + (size_t)N_NODES * 32); // N
    float* ad_      = as_ + N_NODES;                       // N
    int*   row_ptr  = (int*)(ad_ + N_NODES);               // N+1
    int*   csr_src  = row_ptr + N_NODES + 1;               // E+N
    unsigned int* packed = (unsigned int*)(csr_src + NTOT);// NB2*BCAP
    int*   bcur     = (int*)(packed + (size_t)NB2 * BCAP); // NB2

    hipMemsetAsync(bcur, 0, NB2 * sizeof(int), stream);
    bucket_scatter2<<<PB, 256, 0, stream>>>(eidx, bcur, packed);
    csr_build2<<<NB2, 256, 0, stream>>>(packed, bcur, row_ptr, csr_src);

    gemm_in_mfma<<<(N_NODES + 63) / 64, 256, 0, stream>>>(x, W_in, b_in, h);

    unsigned* hin = h;
    unsigned* hx  = hw;
    int mblocks = (N_NODES + 63) / 64;
    int ablocks = (N_NODES + 3) / 4;
    for (int l = 0; l < L_LAYERS; ++l) {
        gemm_mfma_kernel<<<mblocks, 256, 0, stream>>>(
            hin, Wc + l * H_DIM * H_DIM,
            a_src + l * H_DIM, a_dst + l * H_DIM, hx, as_, ad_);
        if (l < L_LAYERS - 1) {
            agg_kernel<<<ablocks, 256, 0, stream>>>(
                row_ptr, csr_src, as_, ad_, hx, bc + l * H_DIM, hin);
        } else {
            agg_out_kernel<<<ablocks, 256, 0, stream>>>(
                row_ptr, csr_src, as_, ad_, hx, bc + l * H_DIM,
                W_out, b_out, out);
        }
    }
}

// Round 16
// 305.484 us; speedup vs baseline: 1.0350x; 1.0350x over previous
//
#include <hip/hip_runtime.h>

#define N_NODES 100000
#define E_EDGES 1600000
#define F_IN    128
#define H_DIM   64
#define C_OUT   16
#define L_LAYERS 3
#define NTOT    (E_EDGES + N_NODES)
#define MAXD    64    // LDS-staged degree cap in agg; fallback recomputes

#define BKN2    512
#define NB2     ((N_NODES + BKN2 - 1) / BKN2)         // 196
#define BCAP    9216
#define CH      8192
#define PB      ((E_EDGES + CH - 1) / CH)             // 196

typedef __attribute__((ext_vector_type(8))) short short8;
typedef __attribute__((ext_vector_type(4))) float f32x4;

// bf16 helpers
__device__ inline unsigned short f2bf(float f) {
    unsigned u = __float_as_uint(f);
    return (unsigned short)((u + 0x7FFFu + ((u >> 16) & 1u)) >> 16);
}
__device__ inline float bf_lo(unsigned p) { return __uint_as_float(p << 16); }
__device__ inline float bf_hi(unsigned p) { return __uint_as_float(p & 0xFFFF0000u); }
__device__ inline unsigned cvt_pk_bf16(float lo, float hi) {
    unsigned r;
    asm("v_cvt_pk_bf16_f32 %0, %1, %2" : "=v"(r) : "v"(lo), "v"(hi));
    return r;
}

// ---------------- pass B: block-local bucket sort + dense scatter ----------------
__global__ __launch_bounds__(256) void bucket_scatter2(
        const void* __restrict__ eidx,
        int* __restrict__ bcur, unsigned int* __restrict__ packed) {
    __shared__ int cnt[NB2], basel[NB2], curl[NB2], gbase[NB2];
    __shared__ int sd[256];
    __shared__ int sflag;
    __shared__ unsigned int stage[CH];
    __shared__ unsigned char bkt[CH];
    int t = threadIdx.x;
    int b0 = blockIdx.x * CH;
    int ne = min(CH, E_EDGES - b0);
    if (t == 0) sflag = 0;
    for (int i = t; i < NB2; i += 256) cnt[i] = 0;
    __syncthreads();
    {
        int nsamp = min(ne, 1024);
        int any = 0;
        for (int j = t; j < nsamp; j += 256)
            if (((const unsigned*)eidx)[2 * (size_t)(b0 + j) + 1] != 0u) any = 1;
        if (any) atomicOr(&sflag, 1);
    }
    __syncthreads();
    int f64 = sflag ? 0 : 1;

    int es[CH / 256], ed[CH / 256];
    #pragma unroll
    for (int j = 0; j < CH / 256; ++j) {
        int idx = b0 + j * 256 + t;
        if (idx < E_EDGES) {
            if (f64) {
                es[j] = (int)((const long long*)eidx)[idx];
                ed[j] = (int)((const long long*)eidx)[E_EDGES + idx];
            } else {
                es[j] = ((const int*)eidx)[idx];
                ed[j] = ((const int*)eidx)[E_EDGES + idx];
            }
            atomicAdd(&cnt[ed[j] >> 9], 1);
        } else { es[j] = -1; }
    }
    __syncthreads();
    int v = (t < NB2) ? cnt[t] : 0;
    sd[t] = v;
    __syncthreads();
    for (int off = 1; off < 256; off <<= 1) {
        int u = (t >= off) ? sd[t - off] : 0;
        __syncthreads();
        sd[t] += u;
        __syncthreads();
    }
    if (t < NB2) {
        basel[t] = sd[t] - v;
        curl[t] = 0;
        gbase[t] = atomicAdd(&bcur[t], v);
    }
    __syncthreads();
    #pragma unroll
    for (int j = 0; j < CH / 256; ++j) {
        if (es[j] >= 0) {
            int b = ed[j] >> 9;
            int r = atomicAdd(&curl[b], 1);
            int pos = basel[b] + r;
            stage[pos] = ((unsigned)(ed[j] & (BKN2 - 1)) << 17) | (unsigned)es[j];
            bkt[pos] = (unsigned char)b;
        }
    }
    __syncthreads();
    for (int i = t; i < ne; i += 256) {
        int b = bkt[i];
        packed[(size_t)b * BCAP + gbase[b] + (i - basel[b])] = stage[i];
    }
}

// ---------------- pass C: per-bucket CSR finalize (inline bucket prefix) ------
__global__ __launch_bounds__(256) void csr_build2(
        const unsigned int* __restrict__ packed, const int* __restrict__ bcur,
        int* __restrict__ row_ptr, int* __restrict__ csr_src) {
    __shared__ int cnt[BKN2], scn[BKN2], cur[BKN2];
    int b = blockIdx.x, t = threadIdx.x;
    scn[t] = (t < b) ? bcur[t] : 0;
    __syncthreads();
    for (int off = 128; off >= 1; off >>= 1) {
        if (t < off) scn[t] += scn[t + off];
        __syncthreads();
    }
    int ebase_b = scn[0];
    __syncthreads();

    int nbase = b * BKN2;
    int nn = min(BKN2, N_NODES - nbase);
    int ec = bcur[b];
    size_t pbase = (size_t)b * BCAP;
    int cbase = ebase_b + nbase;
    cnt[t] = (t < nn) ? 1 : 0;
    cnt[t + 256] = (t + 256 < nn) ? 1 : 0;
    __syncthreads();
    for (int i = t; i < ec; i += 256)
        atomicAdd(&cnt[packed[pbase + i] >> 17], 1);
    __syncthreads();
    scn[t] = cnt[t];
    scn[t + 256] = cnt[t + 256];
    __syncthreads();
    for (int off = 1; off < BKN2; off <<= 1) {
        int u0 = (t >= off) ? scn[t - off] : 0;
        int u1 = (t + 256 >= off) ? scn[t + 256 - off] : 0;
        __syncthreads();
        scn[t] += u0;
        scn[t + 256] += u1;
        __syncthreads();
    }
    #pragma unroll
    for (int q = 0; q < 2; ++q) {
        int idx = t + q * 256;
        if (idx < nn) {
            int offi = scn[idx] - cnt[idx];
            row_ptr[nbase + idx] = cbase + offi;
            csr_src[cbase + offi] = nbase + idx;   // self-loop first
            cur[idx] = offi + 1;
        }
    }
    if (b == NB2 - 1 && t == 0) row_ptr[N_NODES] = cbase + ec + nn;
    __syncthreads();
    for (int i = t; i < ec; i += 256) {
        unsigned p = packed[pbase + i];
        int dl = p >> 17, s = (int)(p & 0x1FFFFu);
        int pos = atomicAdd(&cur[dl], 1);
        csr_src[cbase + pos] = s;
    }
}

// ---------------- MFMA input GEMM (R13 exact) ----------------
#define SAW 136   // bf16 row stride for sA/sWT (pad 8)

__global__ __launch_bounds__(256) void gemm_in_mfma(
        const float* __restrict__ X, const float* __restrict__ W,
        const float* __restrict__ bias, unsigned* __restrict__ C) {
    __shared__ __align__(16) unsigned short sA[64][SAW];
    __shared__ __align__(16) unsigned short sWT[64][SAW];
    __shared__ float sB[64];
    int t = threadIdx.x;
    int r0 = blockIdx.x * 64;
    #pragma unroll
    for (int it = 0; it < 8; ++it) {
        int idx = it * 256 + t;
        int r = idx >> 5, c4 = (idx & 31) * 4;
        int gr = r0 + r;
        float4 v = make_float4(0.f, 0.f, 0.f, 0.f);
        if (gr < N_NODES) v = *(const float4*)&X[(size_t)gr * F_IN + c4];
        unsigned* dst = (unsigned*)&sA[r][c4];
        dst[0] = cvt_pk_bf16(v.x, v.y);
        dst[1] = cvt_pk_bf16(v.z, v.w);
    }
    #pragma unroll
    for (int it = 0; it < 8; ++it) {
        int idx = it * 256 + t;
        int k = idx >> 4, j4 = (idx & 15) * 4;
        float4 v = *(const float4*)&W[k * 64 + j4];
        sWT[j4 + 0][k] = f2bf(v.x);
        sWT[j4 + 1][k] = f2bf(v.y);
        sWT[j4 + 2][k] = f2bf(v.z);
        sWT[j4 + 3][k] = f2bf(v.w);
    }
    if (t < 64) sB[t] = bias[t];
    __syncthreads();

    int wave = t >> 6, lane = t & 63;
    int cj = lane & 15, kq = lane >> 4;
    int lrow = wave * 16 + cj;
    f32x4 zero = {0.f, 0.f, 0.f, 0.f};
    f32x4 acc[4] = {zero, zero, zero, zero};
    #pragma unroll
    for (int q = 0; q < 4; ++q) {
        short8 a = *(const short8*)&sA[lrow][q * 32 + kq * 8];
        #pragma unroll
        for (int ct = 0; ct < 4; ++ct) {
            short8 bfr = *(const short8*)&sWT[ct * 16 + cj][q * 32 + kq * 8];
            acc[ct] = __builtin_amdgcn_mfma_f32_16x16x32_bf16(a, bfr, acc[ct], 0, 0, 0);
        }
    }
    __syncthreads();
    float* tl = (float*)&sA[0][0] + wave * (16 * 65);
    #pragma unroll
    for (int ct = 0; ct < 4; ++ct) {
        float bsv = sB[ct * 16 + cj];
        #pragma unroll
        for (int r = 0; r < 4; ++r) {
            float v = acc[ct][r] + bsv;
            v = v > 0.f ? v : 0.01f * v;
            tl[(kq * 4 + r) * 65 + ct * 16 + cj] = v;
        }
    }
    unsigned ur[8];
    int trow = lane >> 2, tcb = lane & 3;
    #pragma unroll
    for (int i = 0; i < 8; ++i) {
        float2 fp = *(const float2*)&tl[trow * 65 + tcb * 16 + i * 2];
        ur[i] = cvt_pk_bf16(fp.x, fp.y);
    }
    int grow = r0 + wave * 16 + trow;
    if (grow < N_NODES) {
        uint4* dst = (uint4*)&C[(size_t)grow * 32 + tcb * 8];
        dst[0] = make_uint4(ur[0], ur[1], ur[2], ur[3]);
        dst[1] = make_uint4(ur[4], ur[5], ur[6], ur[7]);
    }
}

// ---------------- MFMA layer GEMM (R13 exact) ----------------
__global__ __launch_bounds__(256) void gemm_mfma_kernel(
        const unsigned* __restrict__ A32, const float* __restrict__ W,
        const float* __restrict__ asrc, const float* __restrict__ adst,
        unsigned* __restrict__ C, float* __restrict__ as_, float* __restrict__ ad_) {
    __shared__ __align__(16) unsigned short sWT[64][72];
    __shared__ float sAv[64], sDv[64];
    __shared__ __align__(16) float sTile[4][16 * 65];
    int t = threadIdx.x;
    for (int i = t; i < 64 * 64; i += 256) {
        int k = i >> 6, j = i & 63;
        sWT[j][k] = f2bf(W[i]);
    }
    if (t < 64) { sAv[t] = asrc[t]; sDv[t] = adst[t]; }
    __syncthreads();

    int wave = t >> 6, lane = t & 63;
    int r0 = blockIdx.x * 64 + wave * 16;
    int cj = lane & 15, kq = lane >> 4;

    int ra = r0 + cj;
    if (ra >= N_NODES) ra = N_NODES - 1;
    const short8* arow = (const short8*)&A32[(size_t)ra * 32];
    short8 a0 = arow[kq];
    short8 a1 = arow[4 + kq];

    f32x4 zero = {0.f, 0.f, 0.f, 0.f};
    f32x4 acc[4] = {zero, zero, zero, zero};
    #pragma unroll
    for (int ct = 0; ct < 4; ++ct) {
        short8 b0 = *(const short8*)&sWT[16 * ct + cj][kq * 8];
        short8 b1 = *(const short8*)&sWT[16 * ct + cj][32 + kq * 8];
        acc[ct] = __builtin_amdgcn_mfma_f32_16x16x32_bf16(a0, b0, acc[ct], 0, 0, 0);
        acc[ct] = __builtin_amdgcn_mfma_f32_16x16x32_bf16(a1, b1, acc[ct], 0, 0, 0);
    }

    float av[4], dv[4];
    #pragma unroll
    for (int ct = 0; ct < 4; ++ct) { av[ct] = sAv[ct * 16 + cj]; dv[ct] = sDv[ct * 16 + cj]; }
    #pragma unroll
    for (int r = 0; r < 4; ++r) {
        float ds = acc[0][r] * av[0] + acc[1][r] * av[1] + acc[2][r] * av[2] + acc[3][r] * av[3];
        float dd = acc[0][r] * dv[0] + acc[1][r] * dv[1] + acc[2][r] * dv[2] + acc[3][r] * dv[3];
        #pragma unroll
        for (int off = 1; off < 16; off <<= 1) {
            ds += __shfl_xor(ds, off);
            dd += __shfl_xor(dd, off);
        }
        int grow = r0 + kq * 4 + r;
        if (cj == 0 && grow < N_NODES) { as_[grow] = ds; ad_[grow] = dd; }
    }

    float* tl = sTile[wave];
    #pragma unroll
    for (int ct = 0; ct < 4; ++ct)
        #pragma unroll
        for (int r = 0; r < 4; ++r)
            tl[(kq * 4 + r) * 65 + ct * 16 + cj] = acc[ct][r];
    unsigned ur[8];
    int trow = lane >> 2, tcb = lane & 3;
    #pragma unroll
    for (int i = 0; i < 8; ++i) {
        float2 fp = *(const float2*)&tl[trow * 65 + tcb * 16 + i * 2];
        ur[i] = cvt_pk_bf16(fp.x, fp.y);
    }
    int grow = r0 + trow;
    if (grow < N_NODES) {
        uint4* dst = (uint4*)&C[(size_t)grow * 32 + tcb * 8];
        dst[0] = make_uint4(ur[0], ur[1], ur[2], ur[3]);
        dst[1] = make_uint4(ur[4], ur[5], ur[6], ur[7]);
    }
}

// ---------------- aggregation (R13 exact: 16-lane groups, 2-deep unroll) ----
__global__ __launch_bounds__(256) void agg_kernel(
        const int* __restrict__ row_ptr, const int* __restrict__ csr_src,
        const float* __restrict__ as_, const float* __restrict__ ad_,
        const unsigned* __restrict__ hw32, const float* __restrict__ bc,
        unsigned* __restrict__ hout32) {
    __shared__ float exbuf[4][MAXD];
    __shared__ int   sbuf[4][MAXD];
    int wave = threadIdx.x >> 6, lane = threadIdx.x & 63;
    int node = blockIdx.x * 4 + wave;
    if (node >= N_NODES) return;
    int rs = row_ptr[node], re = row_ptr[node + 1];
    int deg = re - rs;
    float aD = ad_[node];
    float psum = 0.f;
    for (int i = lane; i < deg; i += 64) {
        int s = csr_src[rs + i];
        float v = as_[s] + aD;
        v = v > 0.f ? v : 0.2f * v;
        float p = __expf(v);
        if (deg <= MAXD) { exbuf[wave][i] = p; sbuf[wave][i] = s; }
        psum += p;
    }
    #pragma unroll
    for (int off = 32; off >= 1; off >>= 1) psum += __shfl_xor(psum, off);
    float inv = 1.f / (psum + 1e-16f);

    int g = lane >> 4, fl16 = lane & 15;
    float a0 = 0.f, a1 = 0.f, a2 = 0.f, a3 = 0.f;
    if (deg <= MAXD) {
        int i = g;
        for (; i + 4 < deg; i += 8) {
            float w0 = exbuf[wave][i], w1 = exbuf[wave][i + 4];
            int s0 = sbuf[wave][i], s1 = sbuf[wave][i + 4];
            uint2 p0 = *(const uint2*)&hw32[((unsigned)s0 << 5) | (fl16 * 2)];
            uint2 p1 = *(const uint2*)&hw32[((unsigned)s1 << 5) | (fl16 * 2)];
            a0 += w0 * bf_lo(p0.x) + w1 * bf_lo(p1.x);
            a1 += w0 * bf_hi(p0.x) + w1 * bf_hi(p1.x);
            a2 += w0 * bf_lo(p0.y) + w1 * bf_lo(p1.y);
            a3 += w0 * bf_hi(p0.y) + w1 * bf_hi(p1.y);
        }
        for (; i < deg; i += 4) {
            float w = exbuf[wave][i];
            int s = sbuf[wave][i];
            uint2 p = *(const uint2*)&hw32[((unsigned)s << 5) | (fl16 * 2)];
            a0 += w * bf_lo(p.x);
            a1 += w * bf_hi(p.x);
            a2 += w * bf_lo(p.y);
            a3 += w * bf_hi(p.y);
        }
    } else {
        for (int i = g; i < deg; i += 4) {
            int s = csr_src[rs + i];
            float v = as_[s] + aD;
            v = v > 0.f ? v : 0.2f * v;
            float w = __expf(v);
            uint2 p = *(const uint2*)&hw32[((unsigned)s << 5) | (fl16 * 2)];
            a0 += w * bf_lo(p.x);
            a1 += w * bf_hi(p.x);
            a2 += w * bf_lo(p.y);
            a3 += w * bf_hi(p.y);
        }
    }
    a0 += __shfl_xor(a0, 16); a0 += __shfl_xor(a0, 32);
    a1 += __shfl_xor(a1, 16); a1 += __shfl_xor(a1, 32);
    a2 += __shfl_xor(a2, 16); a2 += __shfl_xor(a2, 32);
    a3 += __shfl_xor(a3, 16); a3 += __shfl_xor(a3, 32);
    if (g == 0) {
        float4 bv = *(const float4*)&bc[fl16 * 4];
        float v0 = a0 * inv + bv.x; v0 = v0 > 0.f ? v0 : 0.01f * v0;
        float v1 = a1 * inv + bv.y; v1 = v1 > 0.f ? v1 : 0.01f * v1;
        float v2 = a2 * inv + bv.z; v2 = v2 > 0.f ? v2 : 0.01f * v2;
        float v3 = a3 * inv + bv.w; v3 = v3 > 0.f ? v3 : 0.01f * v3;
        *(uint2*)&hout32[((unsigned)node << 5) | (fl16 * 2)] =
            make_uint2(cvt_pk_bf16(v0, v1), cvt_pk_bf16(v2, v3));
    }
}

// ---------------- layer-3 aggregation + output GEMM + log_softmax -----------
// R15 body; epilogue rewritten to use ALL 64 lanes for the 64x16 logits dot:
// lane (g,fl16) partials k in [16g,16g+16) for col fl16 (16 FMA + 32 ds_read
// per wave vs 64/128 on 16 lanes), fold via shfl_xor(16,32).
__global__ __launch_bounds__(256) void agg_out_kernel(
        const int* __restrict__ row_ptr, const int* __restrict__ csr_src,
        const float* __restrict__ as_, const float* __restrict__ ad_,
        const unsigned* __restrict__ hw32, const float* __restrict__ bc,
        const float* __restrict__ Wo, const float* __restrict__ bo,
        float* __restrict__ out) {
    __shared__ float exbuf[4][MAXD];
    __shared__ int   sbuf[4][MAXD];
    __shared__ float sh[4][64];
    __shared__ float sWo[64 * 16];
    __shared__ float sbo[16];
    int t = threadIdx.x;
    for (int i = t; i < 64 * 16; i += 256) sWo[i] = Wo[i];
    if (t < 16) sbo[t] = bo[t];
    __syncthreads();

    int wave = t >> 6, lane = t & 63;
    int node = blockIdx.x * 4 + wave;
    if (node >= N_NODES) return;
    int rs = row_ptr[node], re = row_ptr[node + 1];
    int deg = re - rs;
    float aD = ad_[node];
    float psum = 0.f;
    for (int i = lane; i < deg; i += 64) {
        int s = csr_src[rs + i];
        float v = as_[s] + aD;
        v = v > 0.f ? v : 0.2f * v;
        float p = __expf(v);
        if (deg <= MAXD) { exbuf[wave][i] = p; sbuf[wave][i] = s; }
        psum += p;
    }
    #pragma unroll
    for (int off = 32; off >= 1; off >>= 1) psum += __shfl_xor(psum, off);
    float inv = 1.f / (psum + 1e-16f);

    int g = lane >> 4, fl16 = lane & 15;
    float a0 = 0.f, a1 = 0.f, a2 = 0.f, a3 = 0.f;
    if (deg <= MAXD) {
        int i = g;
        for (; i + 4 < deg; i += 8) {
            float w0 = exbuf[wave][i], w1 = exbuf[wave][i + 4];
            int s0 = sbuf[wave][i], s1 = sbuf[wave][i + 4];
            uint2 p0 = *(const uint2*)&hw32[((unsigned)s0 << 5) | (fl16 * 2)];
            uint2 p1 = *(const uint2*)&hw32[((unsigned)s1 << 5) | (fl16 * 2)];
            a0 += w0 * bf_lo(p0.x) + w1 * bf_lo(p1.x);
            a1 += w0 * bf_hi(p0.x) + w1 * bf_hi(p1.x);
            a2 += w0 * bf_lo(p0.y) + w1 * bf_lo(p1.y);
            a3 += w0 * bf_hi(p0.y) + w1 * bf_hi(p1.y);
        }
        for (; i < deg; i += 4) {
            float w = exbuf[wave][i];
            int s = sbuf[wave][i];
            uint2 p = *(const uint2*)&hw32[((unsigned)s << 5) | (fl16 * 2)];
            a0 += w * bf_lo(p.x);
            a1 += w * bf_hi(p.x);
            a2 += w * bf_lo(p.y);
            a3 += w * bf_hi(p.y);
        }
    } else {
        for (int i = g; i < deg; i += 4) {
            int s = csr_src[rs + i];
            float v = as_[s] + aD;
            v = v > 0.f ? v : 0.2f * v;
            float w = __expf(v);
            uint2 p = *(const uint2*)&hw32[((unsigned)s << 5) | (fl16 * 2)];
            a0 += w * bf_lo(p.x);
            a1 += w * bf_hi(p.x);
            a2 += w * bf_lo(p.y);
            a3 += w * bf_hi(p.y);
        }
    }
    a0 += __shfl_xor(a0, 16); a0 += __shfl_xor(a0, 32);
    a1 += __shfl_xor(a1, 16); a1 += __shfl_xor(a1, 32);
    a2 += __shfl_xor(a2, 16); a2 += __shfl_xor(a2, 32);
    a3 += __shfl_xor(a3, 16); a3 += __shfl_xor(a3, 32);
    if (g == 0) {
        float4 bv = *(const float4*)&bc[fl16 * 4];
        float v0 = a0 * inv + bv.x; v0 = v0 > 0.f ? v0 : 0.01f * v0;
        float v1 = a1 * inv + bv.y; v1 = v1 > 0.f ? v1 : 0.01f * v1;
        float v2 = a2 * inv + bv.z; v2 = v2 > 0.f ? v2 : 0.01f * v2;
        float v3 = a3 * inv + bv.w; v3 = v3 > 0.f ? v3 : 0.01f * v3;
        sh[wave][fl16 * 4 + 0] = v0;
        sh[wave][fl16 * 4 + 1] = v1;
        sh[wave][fl16 * 4 + 2] = v2;
        sh[wave][fl16 * 4 + 3] = v3;
    }
    // wave-local RAW on sh (compiler inserts lgkmcnt); all 64 lanes compute
    float acc = 0.f;
    #pragma unroll
    for (int kk = 0; kk < 16; ++kk) {
        int k = g * 16 + kk;
        acc += sh[wave][k] * sWo[k * 16 + fl16];
    }
    acc += __shfl_xor(acc, 16);
    acc += __shfl_xor(acc, 32);
    if (g == 0) {
        acc += sbo[fl16];
        float m = acc;
        #pragma unroll
        for (int off = 8; off >= 1; off >>= 1) m = fmaxf(m, __shfl_xor(m, off, 16));
        float e = __expf(acc - m);
        float ssum = e;
        #pragma unroll
        for (int off = 8; off >= 1; off >>= 1) ssum += __shfl_xor(ssum, off, 16);
        out[(size_t)node * C_OUT + fl16] = acc - m - __logf(ssum);
    }
}

extern "C" void kernel_launch(void* const* d_in, const int* in_sizes, int n_in,
                              void* d_out, int out_size, void* d_ws, size_t ws_size,
                              hipStream_t stream) {
    const float* x     = (const float*)d_in[0];
    const void*  eidx  = d_in[1];
    const float* W_in  = (const float*)d_in[3];
    const float* b_in  = (const float*)d_in[4];
    const float* Wc    = (const float*)d_in[5];
    const float* a_src = (const float*)d_in[6];
    const float* a_dst = (const float*)d_in[7];
    const float* bc    = (const float*)d_in[8];
    const float* W_out = (const float*)d_in[9];
    const float* b_out = (const float*)d_in[10];
    float* out = (float*)d_out;

    // workspace: h, hw packed-bf16 node tables (N x 32 uints)
    unsigned* h     = (unsigned*)d_ws;                     // N*32 uints
    unsigned* hw    = h + (size_t)N_NODES * 32;            // N*32 uints
    float* as_      = (float*)(hw + (size_t)N_NODES * 32); // N
    float* ad_      = as_ + N_NODES;                       // N
    int*   row_ptr  = (int*)(ad_ + N_NODES);               // N+1
    int*   csr_src  = row_ptr + N_NODES + 1;               // E+N
    unsigned int* packed = (unsigned int*)(csr_src + NTOT);// NB2*BCAP
    int*   bcur     = (int*)(packed + (size_t)NB2 * BCAP); // NB2

    hipMemsetAsync(bcur, 0, NB2 * sizeof(int), stream);
    bucket_scatter2<<<PB, 256, 0, stream>>>(eidx, bcur, packed);
    csr_build2<<<NB2, 256, 0, stream>>>(packed, bcur, row_ptr, csr_src);

    gemm_in_mfma<<<(N_NODES + 63) / 64, 256, 0, stream>>>(x, W_in, b_in, h);

    unsigned* hin = h;
    unsigned* hx  = hw;
    int mblocks = (N_NODES + 63) / 64;
    int ablocks = (N_NODES + 3) / 4;
    for (int l = 0; l < L_LAYERS; ++l) {
        gemm_mfma_kernel<<<mblocks, 256, 0, stream>>>(
            hin, Wc + l * H_DIM * H_DIM,
            a_src + l * H_DIM, a_dst + l * H_DIM, hx, as_, ad_);
        if (l < L_LAYERS - 1) {
            agg_kernel<<<ablocks, 256, 0, stream>>>(
                row_ptr, csr_src, as_, ad_, hx, bc + l * H_DIM, hin);
        } else {
            agg_out_kernel<<<ablocks, 256, 0, stream>>>(
                row_ptr, csr_src, as_, ad_, hx, bc + l * H_DIM,
                W_out, b_out, out);
        }
    }
}

// Round 17
// 295.285 us; speedup vs baseline: 1.0708x; 1.0345x over previous
//
#include <hip/hip_runtime.h>

#define N_NODES 100000
#define E_EDGES 1600000
#define F_IN    128
#define H_DIM   64
#define C_OUT   16
#define L_LAYERS 3
#define NTOT    (E_EDGES + N_NODES)
#define MAXD    64    // LDS-staged degree cap in agg; fallback recomputes

#define BKN2    512
#define NB2     ((N_NODES + BKN2 - 1) / BKN2)         // 196
#define BCAP    9216
#define CH      8192
#define PB      ((E_EDGES + CH - 1) / CH)             // 196

typedef __attribute__((ext_vector_type(8))) short short8;
typedef __attribute__((ext_vector_type(4))) float f32x4;

// bf16 helpers
__device__ inline unsigned short f2bf(float f) {
    unsigned u = __float_as_uint(f);
    return (unsigned short)((u + 0x7FFFu + ((u >> 16) & 1u)) >> 16);
}
__device__ inline float bf_lo(unsigned p) { return __uint_as_float(p << 16); }
__device__ inline float bf_hi(unsigned p) { return __uint_as_float(p & 0xFFFF0000u); }
__device__ inline unsigned cvt_pk_bf16(float lo, float hi) {
    unsigned r;
    asm("v_cvt_pk_bf16_f32 %0, %1, %2" : "=v"(r) : "v"(lo), "v"(hi));
    return r;
}

// ---------------- pass B: block-local bucket sort + dense scatter ----------------
__global__ __launch_bounds__(256) void bucket_scatter2(
        const void* __restrict__ eidx,
        int* __restrict__ bcur, unsigned int* __restrict__ packed) {
    __shared__ int cnt[NB2], basel[NB2], curl[NB2], gbase[NB2];
    __shared__ int sd[256];
    __shared__ int sflag;
    __shared__ unsigned int stage[CH];
    __shared__ unsigned char bkt[CH];
    int t = threadIdx.x;
    int b0 = blockIdx.x * CH;
    int ne = min(CH, E_EDGES - b0);
    if (t == 0) sflag = 0;
    for (int i = t; i < NB2; i += 256) cnt[i] = 0;
    __syncthreads();
    {
        int nsamp = min(ne, 1024);
        int any = 0;
        for (int j = t; j < nsamp; j += 256)
            if (((const unsigned*)eidx)[2 * (size_t)(b0 + j) + 1] != 0u) any = 1;
        if (any) atomicOr(&sflag, 1);
    }
    __syncthreads();
    int f64 = sflag ? 0 : 1;

    int es[CH / 256], ed[CH / 256];
    #pragma unroll
    for (int j = 0; j < CH / 256; ++j) {
        int idx = b0 + j * 256 + t;
        if (idx < E_EDGES) {
            if (f64) {
                es[j] = (int)((const long long*)eidx)[idx];
                ed[j] = (int)((const long long*)eidx)[E_EDGES + idx];
            } else {
                es[j] = ((const int*)eidx)[idx];
                ed[j] = ((const int*)eidx)[E_EDGES + idx];
            }
            atomicAdd(&cnt[ed[j] >> 9], 1);
        } else { es[j] = -1; }
    }
    __syncthreads();
    int v = (t < NB2) ? cnt[t] : 0;
    sd[t] = v;
    __syncthreads();
    for (int off = 1; off < 256; off <<= 1) {
        int u = (t >= off) ? sd[t - off] : 0;
        __syncthreads();
        sd[t] += u;
        __syncthreads();
    }
    if (t < NB2) {
        basel[t] = sd[t] - v;
        curl[t] = 0;
        gbase[t] = atomicAdd(&bcur[t], v);
    }
    __syncthreads();
    #pragma unroll
    for (int j = 0; j < CH / 256; ++j) {
        if (es[j] >= 0) {
            int b = ed[j] >> 9;
            int r = atomicAdd(&curl[b], 1);
            int pos = basel[b] + r;
            stage[pos] = ((unsigned)(ed[j] & (BKN2 - 1)) << 17) | (unsigned)es[j];
            bkt[pos] = (unsigned char)b;
        }
    }
    __syncthreads();
    for (int i = t; i < ne; i += 256) {
        int b = bkt[i];
        packed[(size_t)b * BCAP + gbase[b] + (i - basel[b])] = stage[i];
    }
}

// ---------------- pass C: per-bucket CSR finalize (LDS-staged packed) ---------
// One change vs R13: the bucket's packed chunk is staged in LDS once and both
// the count pass and the scatter pass read LDS (saves the 2nd 6.4 MB L2 read).
__global__ __launch_bounds__(256) void csr_build2(
        const unsigned int* __restrict__ packed, const int* __restrict__ bcur,
        int* __restrict__ row_ptr, int* __restrict__ csr_src) {
    __shared__ int cnt[BKN2], scn[BKN2], cur[BKN2];   // 6 KB
    __shared__ unsigned spk[BCAP];                     // 36.9 KB
    int b = blockIdx.x, t = threadIdx.x;
    // ebase = sum_{b'<b} bcur[b'] via block reduce
    scn[t] = (t < b) ? bcur[t] : 0;
    __syncthreads();
    for (int off = 128; off >= 1; off >>= 1) {
        if (t < off) scn[t] += scn[t + off];
        __syncthreads();
    }
    int ebase_b = scn[0];
    __syncthreads();

    int nbase = b * BKN2;
    int nn = min(BKN2, N_NODES - nbase);
    int ec = bcur[b];
    size_t pbase = (size_t)b * BCAP;
    int cbase = ebase_b + nbase;
    cnt[t] = (t < nn) ? 1 : 0;
    cnt[t + 256] = (t + 256 < nn) ? 1 : 0;
    __syncthreads();
    for (int i = t; i < ec; i += 256) {
        unsigned p = packed[pbase + i];
        spk[i] = p;
        atomicAdd(&cnt[p >> 17], 1);
    }
    __syncthreads();
    scn[t] = cnt[t];
    scn[t + 256] = cnt[t + 256];
    __syncthreads();
    for (int off = 1; off < BKN2; off <<= 1) {
        int u0 = (t >= off) ? scn[t - off] : 0;
        int u1 = (t + 256 >= off) ? scn[t + 256 - off] : 0;
        __syncthreads();
        scn[t] += u0;
        scn[t + 256] += u1;
        __syncthreads();
    }
    #pragma unroll
    for (int q = 0; q < 2; ++q) {
        int idx = t + q * 256;
        if (idx < nn) {
            int offi = scn[idx] - cnt[idx];
            row_ptr[nbase + idx] = cbase + offi;
            csr_src[cbase + offi] = nbase + idx;   // self-loop first
            cur[idx] = offi + 1;
        }
    }
    if (b == NB2 - 1 && t == 0) row_ptr[N_NODES] = cbase + ec + nn;
    __syncthreads();
    for (int i = t; i < ec; i += 256) {
        unsigned p = spk[i];
        int dl = p >> 17, s = (int)(p & 0x1FFFFu);
        int pos = atomicAdd(&cur[dl], 1);
        csr_src[cbase + pos] = s;
    }
}

// ---------------- MFMA input GEMM (R13 exact) ----------------
#define SAW 136   // bf16 row stride for sA/sWT (pad 8)

__global__ __launch_bounds__(256) void gemm_in_mfma(
        const float* __restrict__ X, const float* __restrict__ W,
        const float* __restrict__ bias, unsigned* __restrict__ C) {
    __shared__ __align__(16) unsigned short sA[64][SAW];
    __shared__ __align__(16) unsigned short sWT[64][SAW];
    __shared__ float sB[64];
    int t = threadIdx.x;
    int r0 = blockIdx.x * 64;
    #pragma unroll
    for (int it = 0; it < 8; ++it) {
        int idx = it * 256 + t;
        int r = idx >> 5, c4 = (idx & 31) * 4;
        int gr = r0 + r;
        float4 v = make_float4(0.f, 0.f, 0.f, 0.f);
        if (gr < N_NODES) v = *(const float4*)&X[(size_t)gr * F_IN + c4];
        unsigned* dst = (unsigned*)&sA[r][c4];
        dst[0] = cvt_pk_bf16(v.x, v.y);
        dst[1] = cvt_pk_bf16(v.z, v.w);
    }
    #pragma unroll
    for (int it = 0; it < 8; ++it) {
        int idx = it * 256 + t;
        int k = idx >> 4, j4 = (idx & 15) * 4;
        float4 v = *(const float4*)&W[k * 64 + j4];
        sWT[j4 + 0][k] = f2bf(v.x);
        sWT[j4 + 1][k] = f2bf(v.y);
        sWT[j4 + 2][k] = f2bf(v.z);
        sWT[j4 + 3][k] = f2bf(v.w);
    }
    if (t < 64) sB[t] = bias[t];
    __syncthreads();

    int wave = t >> 6, lane = t & 63;
    int cj = lane & 15, kq = lane >> 4;
    int lrow = wave * 16 + cj;
    f32x4 zero = {0.f, 0.f, 0.f, 0.f};
    f32x4 acc[4] = {zero, zero, zero, zero};
    #pragma unroll
    for (int q = 0; q < 4; ++q) {
        short8 a = *(const short8*)&sA[lrow][q * 32 + kq * 8];
        #pragma unroll
        for (int ct = 0; ct < 4; ++ct) {
            short8 bfr = *(const short8*)&sWT[ct * 16 + cj][q * 32 + kq * 8];
            acc[ct] = __builtin_amdgcn_mfma_f32_16x16x32_bf16(a, bfr, acc[ct], 0, 0, 0);
        }
    }
    __syncthreads();
    float* tl = (float*)&sA[0][0] + wave * (16 * 65);
    #pragma unroll
    for (int ct = 0; ct < 4; ++ct) {
        float bsv = sB[ct * 16 + cj];
        #pragma unroll
        for (int r = 0; r < 4; ++r) {
            float v = acc[ct][r] + bsv;
            v = v > 0.f ? v : 0.01f * v;
            tl[(kq * 4 + r) * 65 + ct * 16 + cj] = v;
        }
    }
    unsigned ur[8];
    int trow = lane >> 2, tcb = lane & 3;
    #pragma unroll
    for (int i = 0; i < 8; ++i) {
        float2 fp = *(const float2*)&tl[trow * 65 + tcb * 16 + i * 2];
        ur[i] = cvt_pk_bf16(fp.x, fp.y);
    }
    int grow = r0 + wave * 16 + trow;
    if (grow < N_NODES) {
        uint4* dst = (uint4*)&C[(size_t)grow * 32 + tcb * 8];
        dst[0] = make_uint4(ur[0], ur[1], ur[2], ur[3]);
        dst[1] = make_uint4(ur[4], ur[5], ur[6], ur[7]);
    }
}

// ---------------- MFMA layer GEMM (R13 exact) ----------------
__global__ __launch_bounds__(256) void gemm_mfma_kernel(
        const unsigned* __restrict__ A32, const float* __restrict__ W,
        const float* __restrict__ asrc, const float* __restrict__ adst,
        unsigned* __restrict__ C, float* __restrict__ as_, float* __restrict__ ad_) {
    __shared__ __align__(16) unsigned short sWT[64][72];
    __shared__ float sAv[64], sDv[64];
    __shared__ __align__(16) float sTile[4][16 * 65];
    int t = threadIdx.x;
    for (int i = t; i < 64 * 64; i += 256) {
        int k = i >> 6, j = i & 63;
        sWT[j][k] = f2bf(W[i]);
    }
    if (t < 64) { sAv[t] = asrc[t]; sDv[t] = adst[t]; }
    __syncthreads();

    int wave = t >> 6, lane = t & 63;
    int r0 = blockIdx.x * 64 + wave * 16;
    int cj = lane & 15, kq = lane >> 4;

    int ra = r0 + cj;
    if (ra >= N_NODES) ra = N_NODES - 1;
    const short8* arow = (const short8*)&A32[(size_t)ra * 32];
    short8 a0 = arow[kq];
    short8 a1 = arow[4 + kq];

    f32x4 zero = {0.f, 0.f, 0.f, 0.f};
    f32x4 acc[4] = {zero, zero, zero, zero};
    #pragma unroll
    for (int ct = 0; ct < 4; ++ct) {
        short8 b0 = *(const short8*)&sWT[16 * ct + cj][kq * 8];
        short8 b1 = *(const short8*)&sWT[16 * ct + cj][32 + kq * 8];
        acc[ct] = __builtin_amdgcn_mfma_f32_16x16x32_bf16(a0, b0, acc[ct], 0, 0, 0);
        acc[ct] = __builtin_amdgcn_mfma_f32_16x16x32_bf16(a1, b1, acc[ct], 0, 0, 0);
    }

    float av[4], dv[4];
    #pragma unroll
    for (int ct = 0; ct < 4; ++ct) { av[ct] = sAv[ct * 16 + cj]; dv[ct] = sDv[ct * 16 + cj]; }
    #pragma unroll
    for (int r = 0; r < 4; ++r) {
        float ds = acc[0][r] * av[0] + acc[1][r] * av[1] + acc[2][r] * av[2] + acc[3][r] * av[3];
        float dd = acc[0][r] * dv[0] + acc[1][r] * dv[1] + acc[2][r] * dv[2] + acc[3][r] * dv[3];
        #pragma unroll
        for (int off = 1; off < 16; off <<= 1) {
            ds += __shfl_xor(ds, off);
            dd += __shfl_xor(dd, off);
        }
        int grow = r0 + kq * 4 + r;
        if (cj == 0 && grow < N_NODES) { as_[grow] = ds; ad_[grow] = dd; }
    }

    float* tl = sTile[wave];
    #pragma unroll
    for (int ct = 0; ct < 4; ++ct)
        #pragma unroll
        for (int r = 0; r < 4; ++r)
            tl[(kq * 4 + r) * 65 + ct * 16 + cj] = acc[ct][r];
    unsigned ur[8];
    int trow = lane >> 2, tcb = lane & 3;
    #pragma unroll
    for (int i = 0; i < 8; ++i) {
        float2 fp = *(const float2*)&tl[trow * 65 + tcb * 16 + i * 2];
        ur[i] = cvt_pk_bf16(fp.x, fp.y);
    }
    int grow = r0 + trow;
    if (grow < N_NODES) {
        uint4* dst = (uint4*)&C[(size_t)grow * 32 + tcb * 8];
        dst[0] = make_uint4(ur[0], ur[1], ur[2], ur[3]);
        dst[1] = make_uint4(ur[4], ur[5], ur[6], ur[7]);
    }
}

// ---------------- aggregation (R13 exact: 16-lane groups, 2-deep unroll) ----
__global__ __launch_bounds__(256) void agg_kernel(
        const int* __restrict__ row_ptr, const int* __restrict__ csr_src,
        const float* __restrict__ as_, const float* __restrict__ ad_,
        const unsigned* __restrict__ hw32, const float* __restrict__ bc,
        unsigned* __restrict__ hout32) {
    __shared__ float exbuf[4][MAXD];
    __shared__ int   sbuf[4][MAXD];
    int wave = threadIdx.x >> 6, lane = threadIdx.x & 63;
    int node = blockIdx.x * 4 + wave;
    if (node >= N_NODES) return;
    int rs = row_ptr[node], re = row_ptr[node + 1];
    int deg = re - rs;
    float aD = ad_[node];
    float psum = 0.f;
    for (int i = lane; i < deg; i += 64) {
        int s = csr_src[rs + i];
        float v = as_[s] + aD;
        v = v > 0.f ? v : 0.2f * v;
        float p = __expf(v);
        if (deg <= MAXD) { exbuf[wave][i] = p; sbuf[wave][i] = s; }
        psum += p;
    }
    #pragma unroll
    for (int off = 32; off >= 1; off >>= 1) psum += __shfl_xor(psum, off);
    float inv = 1.f / (psum + 1e-16f);

    int g = lane >> 4, fl16 = lane & 15;
    float a0 = 0.f, a1 = 0.f, a2 = 0.f, a3 = 0.f;
    if (deg <= MAXD) {
        int i = g;
        for (; i + 4 < deg; i += 8) {
            float w0 = exbuf[wave][i], w1 = exbuf[wave][i + 4];
            int s0 = sbuf[wave][i], s1 = sbuf[wave][i + 4];
            uint2 p0 = *(const uint2*)&hw32[((unsigned)s0 << 5) | (fl16 * 2)];
            uint2 p1 = *(const uint2*)&hw32[((unsigned)s1 << 5) | (fl16 * 2)];
            a0 += w0 * bf_lo(p0.x) + w1 * bf_lo(p1.x);
            a1 += w0 * bf_hi(p0.x) + w1 * bf_hi(p1.x);
            a2 += w0 * bf_lo(p0.y) + w1 * bf_lo(p1.y);
            a3 += w0 * bf_hi(p0.y) + w1 * bf_hi(p1.y);
        }
        for (; i < deg; i += 4) {
            float w = exbuf[wave][i];
            int s = sbuf[wave][i];
            uint2 p = *(const uint2*)&hw32[((unsigned)s << 5) | (fl16 * 2)];
            a0 += w * bf_lo(p.x);
            a1 += w * bf_hi(p.x);
            a2 += w * bf_lo(p.y);
            a3 += w * bf_hi(p.y);
        }
    } else {
        for (int i = g; i < deg; i += 4) {
            int s = csr_src[rs + i];
            float v = as_[s] + aD;
            v = v > 0.f ? v : 0.2f * v;
            float w = __expf(v);
            uint2 p = *(const uint2*)&hw32[((unsigned)s << 5) | (fl16 * 2)];
            a0 += w * bf_lo(p.x);
            a1 += w * bf_hi(p.x);
            a2 += w * bf_lo(p.y);
            a3 += w * bf_hi(p.y);
        }
    }
    a0 += __shfl_xor(a0, 16); a0 += __shfl_xor(a0, 32);
    a1 += __shfl_xor(a1, 16); a1 += __shfl_xor(a1, 32);
    a2 += __shfl_xor(a2, 16); a2 += __shfl_xor(a2, 32);
    a3 += __shfl_xor(a3, 16); a3 += __shfl_xor(a3, 32);
    if (g == 0) {
        float4 bv = *(const float4*)&bc[fl16 * 4];
        float v0 = a0 * inv + bv.x; v0 = v0 > 0.f ? v0 : 0.01f * v0;
        float v1 = a1 * inv + bv.y; v1 = v1 > 0.f ? v1 : 0.01f * v1;
        float v2 = a2 * inv + bv.z; v2 = v2 > 0.f ? v2 : 0.01f * v2;
        float v3 = a3 * inv + bv.w; v3 = v3 > 0.f ? v3 : 0.01f * v3;
        *(uint2*)&hout32[((unsigned)node << 5) | (fl16 * 2)] =
            make_uint2(cvt_pk_bf16(v0, v1), cvt_pk_bf16(v2, v3));
    }
}

// ---------------- output GEMM + log_softmax (R13 exact) ----------------
__global__ __launch_bounds__(256) void out_logsoftmax_kernel(
        const unsigned* __restrict__ h32, const float* __restrict__ W,
        const float* __restrict__ b, float* __restrict__ out) {
    __shared__ float sW[H_DIM * C_OUT];
    __shared__ float sh[16][H_DIM];
    __shared__ float sb[C_OUT];
    int t = threadIdx.x;
    for (int i = t; i < H_DIM * C_OUT; i += 256) sW[i] = W[i];
    if (t < C_OUT) sb[t] = b[t];
    int row0 = blockIdx.x * 16;
    #pragma unroll
    for (int it = 0; it < 2; ++it) {
        int idx = it * 256 + t;
        int r = idx >> 5, c2 = idx & 31;
        unsigned u = h32[((unsigned)(row0 + r) << 5) | c2];
        sh[r][c2 * 2] = bf_lo(u);
        sh[r][c2 * 2 + 1] = bf_hi(u);
    }
    __syncthreads();
    int r = t >> 4, c = t & 15;
    float acc = sb[c];
    #pragma unroll
    for (int k = 0; k < H_DIM; ++k) acc += sh[r][k] * sW[k * C_OUT + c];
    float m = acc;
    #pragma unroll
    for (int off = 8; off >= 1; off >>= 1) m = fmaxf(m, __shfl_xor(m, off, 16));
    float e = __expf(acc - m);
    float ssum = e;
    #pragma unroll
    for (int off = 8; off >= 1; off >>= 1) ssum += __shfl_xor(ssum, off, 16);
    out[(row0 + r) * C_OUT + c] = acc - m - __logf(ssum);
}

extern "C" void kernel_launch(void* const* d_in, const int* in_sizes, int n_in,
                              void* d_out, int out_size, void* d_ws, size_t ws_size,
                              hipStream_t stream) {
    const float* x     = (const float*)d_in[0];
    const void*  eidx  = d_in[1];
    const float* W_in  = (const float*)d_in[3];
    const float* b_in  = (const float*)d_in[4];
    const float* Wc    = (const float*)d_in[5];
    const float* a_src = (const float*)d_in[6];
    const float* a_dst = (const float*)d_in[7];
    const float* bc    = (const float*)d_in[8];
    const float* W_out = (const float*)d_in[9];
    const float* b_out = (const float*)d_in[10];
    float* out = (float*)d_out;

    // workspace: h, hw packed-bf16 node tables (N x 32 uints)
    unsigned* h     = (unsigned*)d_ws;                     // N*32 uints
    unsigned* hw    = h + (size_t)N_NODES * 32;            // N*32 uints
    float* as_      = (float*)(hw + (size_t)N_NODES * 32); // N
    float* ad_      = as_ + N_NODES;                       // N
    int*   row_ptr  = (int*)(ad_ + N_NODES);               // N+1
    int*   csr_src  = row_ptr + N_NODES + 1;               // E+N
    unsigned int* packed = (unsigned int*)(csr_src + NTOT);// NB2*BCAP
    int*   bcur     = (int*)(packed + (size_t)NB2 * BCAP); // NB2

    hipMemsetAsync(bcur, 0, NB2 * sizeof(int), stream);
    bucket_scatter2<<<PB, 256, 0, stream>>>(eidx, bcur, packed);
    csr_build2<<<NB2, 256, 0, stream>>>(packed, bcur, row_ptr, csr_src);

    gemm_in_mfma<<<(N_NODES + 63) / 64, 256, 0, stream>>>(x, W_in, b_in, h);

    unsigned* hin = h;
    unsigned* hx  = hw;
    int mblocks = (N_NODES + 63) / 64;
    int ablocks = (N_NODES + 3) / 4;
    for (int l = 0; l < L_LAYERS; ++l) {
        gemm_mfma_kernel<<<mblocks, 256, 0, stream>>>(
            hin, Wc + l * H_DIM * H_DIM,
            a_src + l * H_DIM, a_dst + l * H_DIM, hx, as_, ad_);
        agg_kernel<<<ablocks, 256, 0, stream>>>(
            row_ptr, csr_src, as_, ad_, hx, bc + l * H_DIM, hin);
    }

    out_logsoftmax_kernel<<<N_NODES / 16, 256, 0, stream>>>(hin, W_out, b_out, out);
}